// Round 13
// baseline (217.017 us; speedup 1.0000x reference)
//
#include <hip/hip_runtime.h>

typedef unsigned int u32;
typedef unsigned short u16;
typedef unsigned char u8;
typedef __bf16 bf16x8 __attribute__((ext_vector_type(8)));
typedef float f32x4 __attribute__((ext_vector_type(4)));
typedef float f32x2 __attribute__((ext_vector_type(2)));

__device__ __forceinline__ u16 f2bf(float f) {
  u32 u = __builtin_bit_cast(u32, f);
  u32 r = (u + 0x7fffu + ((u >> 16) & 1u)) >> 16;   // RTNE
  return (u16)r;
}

// ---------------- fused pre-pass: hist | conv x (bf16 + fp8) | conv W ----------------
// bktTotal must be zeroed (hipMemsetAsync) before this kernel.
__global__ __launch_bounds__(256) void pre_k(const float* __restrict__ x, u16* __restrict__ xbf,
                                             u32* __restrict__ xq,
                                             const float* __restrict__ W, u16* __restrict__ wbf,
                                             const int* __restrict__ dst, int E,
                                             u32* __restrict__ bktTotal, int N, int nbkt,
                                             int nba, int nbx) {
  int b = blockIdx.x, tid = threadIdx.x;
  if (b < nba) {                       // histogram over buckets (dst>>8)
    __shared__ u32 h[512];
    for (int t = tid; t < 512; t += 256) h[t] = 0u;
    __syncthreads();
    int base = b * 8192;
    for (int it = 0; it < 32; it++) {
      int i = base + it * 256 + tid;
      if (i < E) atomicAdd(&h[(u32)dst[i] >> 8], 1u);
    }
    __syncthreads();
    for (int t = tid; t < nbkt; t += 256) {
      u32 c = h[t];
      if (c) atomicAdd(&bktTotal[t], c);
    }
  } else if (b < nba + nbx) {          // x -> xbf (bf16) + xq (fp8 e4m3, natural order)
    int i = (b - nba) * 256 + tid;     // i-th float4
    if (i < N * 32) {
      const float4 v = *(const float4*)(x + (size_t)i * 4);
      ushort4 o = { f2bf(v.x), f2bf(v.y), f2bf(v.z), f2bf(v.w) };
      *(ushort4*)(xbf + (size_t)i * 4) = o;
      u32 p = 0;
      p = __builtin_amdgcn_cvt_pk_fp8_f32(v.x, v.y, p, false);
      p = __builtin_amdgcn_cvt_pk_fp8_f32(v.z, v.w, p, true);
      xq[i] = p;
    }
  } else {                             // W (128 x 256 f32) -> bf16
    int i = (b - nba - nbx) * 256 + tid;
    if (i < 8192) {
      const float4 v = *(const float4*)(W + (size_t)i * 4);
      ushort4 o = { f2bf(v.x), f2bf(v.y), f2bf(v.z), f2bf(v.w) };
      *(ushort4*)(wbf + (size_t)i * 4) = o;
    }
  }
}

// ---------------- bucket scan: starts, cursors, offsets[N] ----------------
__global__ __launch_bounds__(512) void bscan_k(const u32* __restrict__ bktTotal, int nbkt,
                                               int E, int N, u32* __restrict__ start,
                                               u32* __restrict__ cursor, u32* __restrict__ offsets) {
  __shared__ u32 s[512];
  int t = threadIdx.x;
  u32 v = (t < nbkt) ? bktTotal[t] : 0u;
  s[t] = v;
  __syncthreads();
  for (int off = 1; off < 512; off <<= 1) {
    u32 x = (t >= off) ? s[t - off] : 0u;
    __syncthreads();
    s[t] += x;
    __syncthreads();
  }
  u32 excl = s[t] - v;
  if (t < nbkt) { start[t] = excl; cursor[t] = excl; }
  if (t == nbkt - 1) start[nbkt] = excl + v;   // == E
  if (t == 0) offsets[N] = (u32)E;
}

// ---------------- pass A2: partition edges into bucket regions (packed u32) ----------------
__global__ __launch_bounds__(256) void part_k(const int* __restrict__ src, const int* __restrict__ dst,
                                              int E, u32* __restrict__ cursor,
                                              u32* __restrict__ packed, int nbkt) {
  __shared__ u32 h[512];
  for (int t = threadIdx.x; t < 512; t += 256) h[t] = 0u;
  __syncthreads();
  int base = blockIdx.x * 8192;
  for (int it = 0; it < 32; it++) {
    int i = base + it * 256 + threadIdx.x;
    if (i < E) atomicAdd(&h[(u32)dst[i] >> 8], 1u);
  }
  __syncthreads();
  for (int t = threadIdx.x; t < nbkt; t += 256) {
    u32 c = h[t];
    h[t] = c ? atomicAdd(&cursor[t], c) : 0u;   // reserve contiguous per-(block,bucket) range
  }
  __syncthreads();
  for (int it = 0; it < 32; it++) {
    int i = base + it * 256 + threadIdx.x;
    if (i < E) {
      u32 d = (u32)dst[i];
      u32 pos = atomicAdd(&h[d >> 8], 1u);      // LDS atomic (u32 fast path)
      packed[pos] = (u32)src[i] | ((d & 255u) << 24);
    }
  }
}

// ---------------- pass B: per-bucket counting sort -> offsets + ssrc + degree-rank perm ----------------
__global__ __launch_bounds__(256) void bucket_k(const u32* __restrict__ packed,
                                                const u32* __restrict__ start, int N,
                                                u32* __restrict__ offsets, int* __restrict__ ssrc,
                                                u8* __restrict__ nodeperm) {
  __shared__ u32 cnt[256];
  __shared__ u32 scn[256];
  __shared__ u32 cur[256];
  int b = blockIdx.x, t = threadIdx.x;
  u32 lo = start[b], hi = start[b + 1];
  cnt[t] = 0u;
  __syncthreads();
  for (u32 j = lo + t; j < hi; j += 256) atomicAdd(&cnt[packed[j] >> 24], 1u);
  __syncthreads();
  u32 v = cnt[t];
  scn[t] = v;
  __syncthreads();
  for (int off = 1; off < 256; off <<= 1) {
    u32 x = (t >= off) ? scn[t - off] : 0u;
    __syncthreads();
    scn[t] += x;
    __syncthreads();
  }
  u32 base = lo + scn[t] - v;     // exclusive position of this node's segment
  int node = b * 256 + t;
  if (node < N) offsets[node] = base;
  cur[t] = base;
  __syncthreads();
  for (u32 j = lo + t; j < hi; j += 256) {
    u32 w = packed[j];
    u32 pos = atomicAdd(&cur[w >> 24], 1u);   // LDS atomic (u32)
    ssrc[pos] = (int)(w & 0xFFFFFFu);
  }
  // degree-rank permutation per 64-node group (ascending degree, stable)
  {
    int g = t >> 6, l = t & 63;
    u32 mykey = cnt[t] * 256u + (u32)l;
    const u32* cg = &cnt[g * 64];
    u32 rank = 0;
#pragma unroll 8
    for (int l2 = 0; l2 < 64; l2++) {
      u32 k2 = cg[l2] * 256u + (u32)l2;
      rank += (k2 < mykey) ? 1u : 0u;
    }
    nodeperm[(size_t)b * 256 + g * 64 + rank] = (u8)l;
  }
}

// ---------------- fused aggregate + GEMM, 4 waves / 64 nodes per block ----------------
// Phase 1: 8-lane subgroups (lane slice = 16B of the 128B fp8 row, dwordx4 loads);
// 8 degree-matched nodes per wave concurrently, 2 rounds; A/B quad ping-pong + idx
// prefetch keeps ~5 KB/wave of gathers in flight.
// Phase 2: per-wave 16-row MFMA strip: A = [xbf rows | LDS means], B = wbf.
#define DECX(vv) { f32x2 p;                                                    \
    p = __builtin_amdgcn_cvt_pk_f32_fp8((vv).x, false); acc[0] += p;           \
    p = __builtin_amdgcn_cvt_pk_f32_fp8((vv).x, true);  acc[1] += p;           \
    p = __builtin_amdgcn_cvt_pk_f32_fp8((vv).y, false); acc[2] += p;           \
    p = __builtin_amdgcn_cvt_pk_f32_fp8((vv).y, true);  acc[3] += p;           \
    p = __builtin_amdgcn_cvt_pk_f32_fp8((vv).z, false); acc[4] += p;           \
    p = __builtin_amdgcn_cvt_pk_f32_fp8((vv).z, true);  acc[5] += p;           \
    p = __builtin_amdgcn_cvt_pk_f32_fp8((vv).w, false); acc[6] += p;           \
    p = __builtin_amdgcn_cvt_pk_f32_fp8((vv).w, true);  acc[7] += p; }

#define ROWS4(R0, R1, R2, R3, I) {                                             \
    R0 = *(const uint4*)(xqb + ((size_t)(I).x << 7) + lofs);                   \
    R1 = *(const uint4*)(xqb + ((size_t)(I).y << 7) + lofs);                   \
    R2 = *(const uint4*)(xqb + ((size_t)(I).z << 7) + lofs);                   \
    R3 = *(const uint4*)(xqb + ((size_t)(I).w << 7) + lofs); }

__global__ __launch_bounds__(256) void fuse_k(const int* __restrict__ ssrc,
                                              const u32* __restrict__ offsets,
                                              const u32* __restrict__ xq,
                                              const u16* __restrict__ xbf,
                                              const u16* __restrict__ wbf,
                                              const float* __restrict__ bias,
                                              const u8* __restrict__ nodeperm,
                                              float* __restrict__ out, int N) {
  __shared__ u16 mlds[64][136];               // padded stride vs bank conflicts
  int wv = threadIdx.x >> 6, lane = threadIdx.x & 63;
  int sub = lane >> 3, c8 = lane & 7;         // 8 subgroups x 8 lanes
  int nbase = blockIdx.x * 64;
  const char* xqb = (const char*)xq;
  const int lofs = c8 << 4;                   // 16B slice within the 128B row

  // ---- phase 1: 2 rounds x 8 concurrent degree-matched nodes per wave ----
  for (int r = 0; r < 2; r++) {
    int ln = nodeperm[(size_t)nbase + r * 32 + wv * 8 + sub];
    int node = nbase + ln;
    f32x2 acc[8];
#pragma unroll
    for (int i = 0; i < 8; i++) acc[i] = f32x2{0.f, 0.f};
    u32 deg = 0;
    if (node < N) {
      u32 s0 = offsets[node], s1 = offsets[node + 1];
      deg = s1 - s0;
      u32 j = s0;
      u32 nq = deg >> 2;
      u32 npair = nq >> 1;
      if (npair) {
        uint4 iA = *(const uint4*)(ssrc + j);
        uint4 iB = *(const uint4*)(ssrc + j + 4);
        uint4 a0, a1, a2, a3, b0, b1, b2, b3;
        ROWS4(a0, a1, a2, a3, iA)
        for (u32 p = 1; p < npair; p++) {
          ROWS4(b0, b1, b2, b3, iB)
          iA = *(const uint4*)(ssrc + j + 8);
          iB = *(const uint4*)(ssrc + j + 12);
          DECX(a0) DECX(a1) DECX(a2) DECX(a3)
          ROWS4(a0, a1, a2, a3, iA)
          DECX(b0) DECX(b1) DECX(b2) DECX(b3)
          j += 8;
        }
        ROWS4(b0, b1, b2, b3, iB)
        DECX(a0) DECX(a1) DECX(a2) DECX(a3)
        DECX(b0) DECX(b1) DECX(b2) DECX(b3)
        j += 8;
      }
      if (nq & 1) {
        uint4 iT = *(const uint4*)(ssrc + j);
        uint4 t0, t1, t2, t3;
        ROWS4(t0, t1, t2, t3, iT)
        DECX(t0) DECX(t1) DECX(t2) DECX(t3)
        j += 4;
      }
      for (; j < s1; j++) {
        int e = ssrc[j];
        uint4 v = *(const uint4*)(xqb + ((size_t)e << 7) + lofs);
        DECX(v)
      }
    }
    float inv = 1.0f / (float)(deg ? deg : 1u);
    u32 o[8];
#pragma unroll
    for (int k = 0; k < 8; k++)
      o[k] = (u32)f2bf(acc[k].x * inv) | ((u32)f2bf(acc[k].y * inv) << 16);
    u32* mp = (u32*)&mlds[ln][c8 * 16];       // 8 lanes cover all 128 feats (16 each)
    *(uint4*)(mp + 0) = uint4{o[0], o[1], o[2], o[3]};
    *(uint4*)(mp + 4) = uint4{o[4], o[5], o[6], o[7]};
  }
  __syncthreads();

  // ---- phase 2: 16-row GEMM strip (K=256: x from global, mean from LDS) ----
  int la = lane & 15, lb = lane >> 4;
  int wbase = nbase + wv * 16;
  bf16x8 a[8];
  const u16* ab = xbf + ((size_t)(wbase + la) << 7) + lb * 8;
#pragma unroll
  for (int kb = 0; kb < 4; kb++) a[kb] = *(const bf16x8*)(ab + kb * 32);
#pragma unroll
  for (int kb = 0; kb < 4; kb++) a[4 + kb] = *(const bf16x8*)(&mlds[wv * 16 + la][kb * 32 + lb * 8]);

#pragma unroll
  for (int ct = 0; ct < 8; ct++) {
    f32x4 accr = { 0.f, 0.f, 0.f, 0.f };
    const u16* bbase = wbf + ((size_t)(ct * 16 + la) << 8) + lb * 8;
#pragma unroll
    for (int kb = 0; kb < 8; kb++) {
      bf16x8 b = *(const bf16x8*)(bbase + kb * 32);
      accr = __builtin_amdgcn_mfma_f32_16x16x32_bf16(a[kb], b, accr, 0, 0, 0);
    }
    float bc = bias[ct * 16 + la];
#pragma unroll
    for (int jj = 0; jj < 4; jj++) {
      int rr = wbase + lb * 4 + jj;
      if (rr < N) out[((size_t)rr << 7) + ct * 16 + la] = accr[jj] + bc;
    }
  }
}

extern "C" void kernel_launch(void* const* d_in, const int* in_sizes, int n_in,
                              void* d_out, int out_size, void* d_ws, size_t ws_size,
                              hipStream_t stream) {
  const float* x    = (const float*)d_in[0];
  const int*   ei   = (const int*)d_in[1];
  const float* W    = (const float*)d_in[2];
  const float* bias = (const float*)d_in[3];
  const int N = in_sizes[0] / 128;
  const int E = in_sizes[1] / 2;
  const int nbkt = (N + 255) >> 8;           // 256-node buckets
  const int* src = ei;
  const int* dst = ei + E;
  float* out = (float*)d_out;

  // transient CSR-build scratch in d_out (dead before fuse_k writes out):
  u32* packed   = (u32*)d_out;               // E
  u32* bktTotal = packed + E;                // nbkt
  u32* start    = bktTotal + nbkt;           // nbkt+1
  u32* cursor   = start + nbkt + 1;          // nbkt

  char* ws = (char*)d_ws;
  u32* offsets = (u32*)ws;                   // N+1
  size_t off = ((size_t)(N + 1) * 4 + 255) & ~(size_t)255;
  int* ssrc = (int*)(ws + off);              // E
  off += (size_t)E * 4;
  off = (off + 255) & ~(size_t)255;
  u16* xbf = (u16*)(ws + off);               // N*128 bf16
  off += (size_t)N * 128 * 2;
  off = (off + 255) & ~(size_t)255;
  u32* xq = (u32*)(ws + off);                // N*32 u32 (natural-order fp8)
  off += (size_t)N * 128;
  off = (off + 255) & ~(size_t)255;
  u16* wbf = (u16*)(ws + off);               // 128*256 bf16
  off += (size_t)128 * 256 * 2;
  off = (off + 255) & ~(size_t)255;
  u8* nodeperm = (u8*)(ws + off);            // nbkt*256 bytes

  const int nbx = (N * 32 + 255) / 256;
  const int nba = (E + 8191) / 8192;
  hipMemsetAsync(bktTotal, 0, (size_t)nbkt * 4, stream);
  pre_k<<<nba + nbx + 32, 256, 0, stream>>>(x, xbf, xq, W, wbf, dst, E, bktTotal, N, nbkt, nba, nbx);
  bscan_k<<<1, 512, 0, stream>>>(bktTotal, nbkt, E, N, start, cursor, offsets);
  part_k<<<nba, 256, 0, stream>>>(src, dst, E, cursor, packed, nbkt);
  bucket_k<<<nbkt, 256, 0, stream>>>(packed, start, N, offsets, ssrc, nodeperm);
  fuse_k<<<(N + 63) / 64, 256, 0, stream>>>(ssrc, offsets, xq, xbf, wbf, bias, nodeperm, out, N);
}